// Round 4
// baseline (28691.278 us; speedup 1.0000x reference)
//
#include <hip/hip_runtime.h>
#include <math.h>

#define NN 5184
#define MM 81
#define BTOT 512
#define NITER 100
#define NSL 32            // n-slots: 162 rows each
#define GRP 8             // batch groups of 64 (XCD-aligned heuristic)
#define NR 162            // rows per WG
#define BR 64             // batches per group (= 64 lanes)
#define THREADS 1024
#define GRID (NSL*GRP)    // 256 WGs, 1/CU forced via LDS
#define RMAX 11           // max rows per wave (2 waves get 11, 14 get 10)
#define YT_STRIDE 65
#define UL_STRIDE 85
#define ZB_STRIDE 96
#define SMEM_BYTES 84000  // >80KB -> exactly 1 WG/CU (co-residency for barriers)

// d_ws layout: cnt[1024] uints (4KB; per-group cells at g*64, global cell at 512),
//              then zbuf[GRP][BR][ZB_STRIDE]  (~197KB total)
// pbuf (u partials) = d_out [GRP][NSL][BR][MM] = 5.3MB (< 10.6MB out)

__global__ void prefill(const float* __restrict__ x, float* __restrict__ zbuf,
                        unsigned* __restrict__ cnt) {
    int i = blockIdx.x * 256 + threadIdx.x;
    if (i < GRP * BR * ZB_STRIDE) {
        int g = i / (BR * ZB_STRIDE);
        int r = i - g * (BR * ZB_STRIDE);
        int b = r / ZB_STRIDE, m = r - b * ZB_STRIDE;
        zbuf[i] = (m < MM) ? x[(size_t)(g * BR + b) * MM + m] : 0.f;
    }
    if (i < 1024) cnt[i] = 0u;
}

__device__ __forceinline__ void grid_barrier(unsigned* cnt, unsigned target) {
    __syncthreads();
    if (threadIdx.x == 0) {
        __hip_atomic_fetch_add(cnt, 1u, __ATOMIC_ACQ_REL, __HIP_MEMORY_SCOPE_AGENT);
        while (__hip_atomic_load(cnt, __ATOMIC_ACQUIRE, __HIP_MEMORY_SCOPE_AGENT) < target)
            __builtin_amdgcn_s_sleep(2);
    }
    __syncthreads();
}

__global__ __launch_bounds__(THREADS, 4) void fista(
        const float* __restrict__ x, const float* __restrict__ mat,
        const float* __restrict__ lam, float* __restrict__ out,
        float* __restrict__ zbuf, unsigned* __restrict__ cntbase) {
    extern __shared__ float sm[];
    float* yT  = sm;                        // [NR][YT_STRIDE]  (used only at end)
    float* uL  = sm + NR * YT_STRIDE;       // [BR][UL_STRIDE]
    float* red = uL + BR * UL_STRIDE;       // [672]

    const int tid  = threadIdx.x;
    const int wv   = tid >> 6, lane = tid & 63;
    const int g    = blockIdx.x & 7;
    const int slot = blockIdx.x >> 3;
    const int b0   = g * BR;
    const int n0   = slot * NR;
    const float thr = lam[0];
    unsigned* cnt  = cntbase + g * 64;      // per-group counter (256B-spaced)
    unsigned* gcnt = cntbase + 512;         // global counter
    float* zb = zbuf + (size_t)g * BR * ZB_STRIDE;
    float* pbuf = out;                      // [GRP][NSL][BR][MM]

    for (int i = tid; i < BR * UL_STRIDE; i += THREADS) uL[i] = 0.f;
    __syncthreads();

    // wave row partition: waves 0,1 get 11 rows, rest 10 (2*11 + 14*10 = 162)
    const int rbeg = wv * 10 + (wv < 2 ? wv : 2);
    const int rcnt = (wv < 2) ? 11 : 10;

    float ya[RMAX];
#pragma unroll
    for (int r = 0; r < RMAX; ++r) ya[r] = 0.f;

    float t = 1.f;
    unsigned bar = 0;

    for (int it = 0; it < NITER; ++it) {
        float tn = (1.f + sqrtf(1.f + t * t)) * 0.5f;
        float coef = (t - 1.f) / tn;
        t = tn;
        const bool dob = (it != NITER - 1);

        // ---- lane b = own z row -> registers (written by prev iter's Phase R) ----
        float za[84];
        {
            const float4* zp = (const float4*)(zb + (size_t)lane * ZB_STRIDE);
#pragma unroll
            for (int i = 0; i < 21; ++i) {
                float4 v = zp[i];
                za[4*i] = v.x; za[4*i+1] = v.y; za[4*i+2] = v.z; za[4*i+3] = v.w;
            }
        }

        float ua[MM];
        if (dob) {
#pragma unroll
            for (int m = 0; m < MM; ++m) ua[m] = 0.f;
        }

        // ---- fused A+B: per owned row, mat row via SGPR (s_load), then
        //      re = <mat_row, z_b>; y update; u_b += y_new * mat_row ----
#pragma unroll
        for (int r = 0; r < RMAX; ++r) {
            if (r < rcnt) {   // wave-uniform guard
                const float* mrow = mat +
                    (size_t)__builtin_amdgcn_readfirstlane(n0 + rbeg + r) * MM;
                float re0 = 0.f, re1 = 0.f, re2 = 0.f, re3 = 0.f;
#pragma unroll
                for (int m = 0; m < 80; m += 4) {
                    re0 = fmaf(mrow[m],     za[m],     re0);
                    re1 = fmaf(mrow[m + 1], za[m + 1], re1);
                    re2 = fmaf(mrow[m + 2], za[m + 2], re2);
                    re3 = fmaf(mrow[m + 3], za[m + 3], re3);
                }
                re0 = fmaf(mrow[80], za[80], re0);
                float re = (re0 + re1) + (re2 + re3);
                float yo = ya[r];
                float w  = yo + re;                                    // MU = 1
                float yn = fmaxf(w - thr, 0.f) + fminf(w + thr, 0.f);  // soft-thresh
                float yv = yn + coef * (yn - yo);                      // momentum
                ya[r] = yv;
                if (dob) {
#pragma unroll
                    for (int m = 0; m < MM; ++m)
                        ua[m] = fmaf(mrow[m], yv, ua[m]);
                }
            }
        }
        if (!dob) break;

        // ---- 16-wave reduce into uL via LDS float atomics (stride 85: 2-way, free) ----
#pragma unroll
        for (int m = 0; m < MM; ++m)
            __hip_atomic_fetch_add(&uL[lane * UL_STRIDE + m], ua[m],
                                   __ATOMIC_RELAXED, __HIP_MEMORY_SCOPE_WORKGROUP);
        __syncthreads();

        // ---- write WG's u partial to pbuf (coalesced) ----
        {
            size_t base = (((size_t)g * NSL + slot) * BR) * MM;
            for (int i = tid; i < BR * MM; i += THREADS) {
                int b = i / MM, m = i - b * MM;
                pbuf[base + i] = uL[b * UL_STRIDE + m];
            }
        }
        __syncthreads();
        for (int i = tid; i < BR * UL_STRIDE; i += THREADS) uL[i] = 0.f;

        grid_barrier(cnt, ++bar * 32u);

        // ---- Phase R: reduce 32 slices for batches 2*slot, 2*slot+1; z = x - u ----
        if (tid < 648) {
            int sq = tid & 3, e = tid >> 2;          // e 0..161
            int b2 = (e >= MM) ? 1 : 0;
            int m  = e - b2 * MM;
            int bg = 2 * slot + b2;
            const float* pp = pbuf + (((size_t)g * NSL) * BR + bg) * MM + m;
            float ssum = 0.f;
#pragma unroll
            for (int s2 = 0; s2 < 8; ++s2)
                ssum += pp[(size_t)(sq * 8 + s2) * BR * MM];
            red[tid] = ssum;
        }
        __syncthreads();
        if (tid < 162) {
            int b2 = (tid >= MM) ? 1 : 0;
            int m  = tid - b2 * MM;
            int bg = 2 * slot + b2;
            float tot = red[tid*4] + red[tid*4+1] + red[tid*4+2] + red[tid*4+3];
            zb[(size_t)bg * ZB_STRIDE + m] = x[(size_t)(b0 + bg) * MM + m] - tot;
        }

        grid_barrier(cnt, ++bar * 32u);
    }

    // ---- GLOBAL barrier: all groups done reading pbuf before out is overwritten ----
    grid_barrier(gcnt, (unsigned)GRID);

    // ---- final y -> LDS transpose -> coalesced out write ----
#pragma unroll
    for (int r = 0; r < RMAX; ++r)
        if (r < rcnt) yT[(rbeg + r) * YT_STRIDE + lane] = ya[r];
    __syncthreads();
    for (int i = tid; i < BR * NR; i += THREADS) {
        int b = i / NR, n = i - b * NR;
        out[(size_t)(b0 + b) * NN + n0 + n] = yT[n * YT_STRIDE + b];
    }
}

extern "C" void kernel_launch(void* const* d_in, const int* in_sizes, int n_in,
                              void* d_out, int out_size, void* d_ws, size_t ws_size,
                              hipStream_t stream) {
    const float* x   = (const float*)d_in[0];   // [512][81]
    const float* mat = (const float*)d_in[1];   // [5184][81]
    const float* lam = (const float*)d_in[2];   // [1]
    float* out = (float*)d_out;                 // [512][5184]

    unsigned* cnt = (unsigned*)d_ws;                 // 1024 uints
    float* zbuf   = (float*)((char*)d_ws + 4096);    // [GRP][BR][ZB_STRIDE]

    hipFuncSetAttribute((const void*)fista,
                        hipFuncAttributeMaxDynamicSharedMemorySize, SMEM_BYTES);
    prefill<<<(GRP * BR * ZB_STRIDE + 255) / 256, 256, 0, stream>>>(x, zbuf, cnt);
    fista<<<GRID, THREADS, SMEM_BYTES, stream>>>(x, mat, lam, out, zbuf, cnt);
}

// Round 5
// 15588.254 us; speedup vs baseline: 1.8406x; 1.8406x over previous
//
#include <hip/hip_runtime.h>
#include <math.h>

#define NN 5184
#define MM 81
#define BTOT 512
#define NITER 100
#define NSL 32            // n-slots: 162 rows each
#define GRP 8             // batch groups of 64 (XCD-aligned heuristic)
#define NR 162            // rows per WG
#define BR 64             // batches per group (= 64 lanes)
#define THREADS 1024
#define GRID (NSL*GRP)    // 256 WGs, 1/CU
#define RMAX 11           // waves 0,1: 11 rows; waves 2..15: 10 rows
#define YT_STRIDE 65
#define UL_STRIDE 85
#define ZG (MM*BR)        // per-group zbT floats (transposed [m][b])
// LDS: yT[162][65] + uL[64][85] + red[672] + zL[81][64]
#define SMEM_FLOATS (NR*YT_STRIDE + BR*UL_STRIDE + 672 + ZG)
#define SMEM_BYTES (SMEM_FLOATS*4)   // 87,304 B -> 1 WG/CU

// d_ws: cnt[1024] uints (4KB; group g at cnt[g*64], global at cnt[512]),
//       then zbT[GRP][MM][BR] (~166KB)
// pbuf (u partials) = d_out [GRP][NSL][BR][MM] = 5.3MB (< 10.6MB out)

__global__ void prefill(const float* __restrict__ x, float* __restrict__ zbT,
                        unsigned* __restrict__ cnt) {
    int i = blockIdx.x * 256 + threadIdx.x;
    if (i < GRP * ZG) {
        int g = i / ZG, r = i - g * ZG;
        int m = r / BR, b = r - m * BR;
        zbT[i] = x[(size_t)(g * BR + b) * MM + m];
    }
    if (i < 1024) cnt[i] = 0u;
}

__device__ __forceinline__ void grid_barrier(unsigned* cnt, unsigned target) {
    __syncthreads();
    if (threadIdx.x == 0) {
        __hip_atomic_fetch_add(cnt, 1u, __ATOMIC_ACQ_REL, __HIP_MEMORY_SCOPE_AGENT);
        while (__hip_atomic_load(cnt, __ATOMIC_ACQUIRE, __HIP_MEMORY_SCOPE_AGENT) < target)
            __builtin_amdgcn_s_sleep(2);
    }
    __syncthreads();
}

__global__ __launch_bounds__(THREADS, 4) void fista(
        const float* __restrict__ x, const float* __restrict__ mat,
        const float* __restrict__ lam, float* __restrict__ out,
        float* __restrict__ zbT, unsigned* __restrict__ cntbase) {
    extern __shared__ float sm[];
    float* yT  = sm;                             // [NR][YT_STRIDE]: y state
    float* uL  = sm + NR * YT_STRIDE;            // [BR][UL_STRIDE]
    float* red = uL + BR * UL_STRIDE;            // [672]
    float* zL  = red + 672;                      // [MM][BR]: z staged per iter

    const int tid  = threadIdx.x;
    const int wv   = tid >> 6, lane = tid & 63;
    const int g    = blockIdx.x & 7;
    const int slot = blockIdx.x >> 3;
    const int b0   = g * BR;
    const int n0   = slot * NR;
    const float thr = lam[0];
    unsigned* cnt  = cntbase + g * 64;           // per-group counter
    unsigned* gcnt = cntbase + 512;              // global counter
    const float* zg = zbT + (size_t)g * ZG;      // group's z (transposed)
    float* zgw = zbT + (size_t)g * ZG;
    float* pbuf = out;                           // [GRP][NSL][BR][MM]

    for (int i = tid; i < BR * UL_STRIDE; i += THREADS) uL[i] = 0.f;
    for (int i = tid; i < NR * YT_STRIDE; i += THREADS) yT[i] = 0.f;

    // wave row partition: waves 0,1 get 11 rows, rest 10 (2*11 + 14*10 = 162)
    const int rbeg = wv * 10 + (wv < 2 ? wv : 2);
    const int rcnt = (wv < 2) ? 11 : 10;

    float t = 1.f;
    unsigned bar = 0;

    for (int it = 0; it < NITER; ++it) {
        float tn = (1.f + sqrtf(1.f + t * t)) * 0.5f;
        float coef = (t - 1.f) / tn;
        t = tn;
        const bool dob = (it != NITER - 1);

        // ---- stage z into LDS (coalesced global read, written by prev Phase R) ----
        __syncthreads();
        for (int i = tid; i < ZG; i += THREADS) zL[i] = zg[i];
        __syncthreads();

        // ---- lane b: z row -> registers (conflict-free ds_read) ----
        float za[MM];
#pragma unroll
        for (int m = 0; m < MM; ++m) za[m] = zL[m * BR + lane];

        // ---- Phase A: re = <mat_row, z_b> (mat row in SGPRs); y update ----
#pragma unroll
        for (int r = 0; r < RMAX; ++r) {
            if (r < rcnt) {   // wave-uniform guard
                const int row = rbeg + r;
                const float* mrow = mat +
                    (size_t)__builtin_amdgcn_readfirstlane(n0 + row) * MM;
                float re0 = 0.f, re1 = 0.f, re2 = 0.f, re3 = 0.f;
#pragma unroll
                for (int m = 0; m < 80; m += 4) {
                    re0 = fmaf(mrow[m],     za[m],     re0);
                    re1 = fmaf(mrow[m + 1], za[m + 1], re1);
                    re2 = fmaf(mrow[m + 2], za[m + 2], re2);
                    re3 = fmaf(mrow[m + 3], za[m + 3], re3);
                }
                re0 = fmaf(mrow[80], za[80], re0);
                float re = (re0 + re1) + (re2 + re3);
                float* yp = &yT[row * YT_STRIDE + lane];
                float yo = *yp;
                float w  = yo + re;                                    // MU = 1
                float yn = fmaxf(w - thr, 0.f) + fminf(w + thr, 0.f);  // soft-thresh
                *yp = yn + coef * (yn - yo);                           // momentum
            }
        }
        if (!dob) break;

        // ---- Phase B: u_b += y[row]_b * mat_row (separate pass: fits 128 VGPR) ----
        {
            float ua[MM];
#pragma unroll
            for (int m = 0; m < MM; ++m) ua[m] = 0.f;
#pragma unroll
            for (int r = 0; r < RMAX; ++r) {
                if (r < rcnt) {
                    const int row = rbeg + r;
                    const float* mrow = mat +
                        (size_t)__builtin_amdgcn_readfirstlane(n0 + row) * MM;
                    float yv = yT[row * YT_STRIDE + lane];
#pragma unroll
                    for (int m = 0; m < MM; ++m)
                        ua[m] = fmaf(mrow[m], yv, ua[m]);
                }
            }
            // 16-wave reduce via LDS float atomics (stride 85 -> 2-way, free)
#pragma unroll
            for (int m = 0; m < MM; ++m)
                __hip_atomic_fetch_add(&uL[lane * UL_STRIDE + m], ua[m],
                                       __ATOMIC_RELAXED, __HIP_MEMORY_SCOPE_WORKGROUP);
        }
        __syncthreads();

        // ---- write WG's u partial to pbuf (coalesced) ----
        {
            size_t base = (((size_t)g * NSL + slot) * BR) * MM;
            for (int i = tid; i < BR * MM; i += THREADS) {
                int b = i / MM, m = i - b * MM;
                pbuf[base + i] = uL[b * UL_STRIDE + m];
            }
        }
        __syncthreads();
        for (int i = tid; i < BR * UL_STRIDE; i += THREADS) uL[i] = 0.f;

        grid_barrier(cnt, ++bar * 32u);

        // ---- Phase R: reduce 32 slices for batches 2*slot, 2*slot+1; z = x - u ----
        if (tid < 648) {
            int sq = tid & 3, e = tid >> 2;          // e 0..161
            int b2 = (e >= MM) ? 1 : 0;
            int m  = e - b2 * MM;
            int bg = 2 * slot + b2;
            const float* pp = pbuf + (((size_t)g * NSL) * BR + bg) * MM + m;
            float ssum = 0.f;
#pragma unroll
            for (int s2 = 0; s2 < 8; ++s2)
                ssum += pp[(size_t)(sq * 8 + s2) * BR * MM];
            red[tid] = ssum;
        }
        __syncthreads();
        if (tid < 162) {
            int b2 = (tid >= MM) ? 1 : 0;
            int m  = tid - b2 * MM;
            int bg = 2 * slot + b2;
            float tot = red[tid*4] + red[tid*4+1] + red[tid*4+2] + red[tid*4+3];
            zgw[m * BR + bg] = x[(size_t)(b0 + bg) * MM + m] - tot;   // transposed store
        }

        grid_barrier(cnt, ++bar * 32u);
    }

    // ---- GLOBAL barrier: all groups done reading pbuf before out is overwritten ----
    grid_barrier(gcnt, (unsigned)GRID);

    // ---- final y: LDS transpose -> coalesced out write ----
    for (int i = tid; i < BR * NR; i += THREADS) {
        int b = i / NR, n = i - b * NR;
        out[(size_t)(b0 + b) * NN + n0 + n] = yT[n * YT_STRIDE + b];
    }
}

extern "C" void kernel_launch(void* const* d_in, const int* in_sizes, int n_in,
                              void* d_out, int out_size, void* d_ws, size_t ws_size,
                              hipStream_t stream) {
    const float* x   = (const float*)d_in[0];   // [512][81]
    const float* mat = (const float*)d_in[1];   // [5184][81]
    const float* lam = (const float*)d_in[2];   // [1]
    float* out = (float*)d_out;                 // [512][5184]

    unsigned* cnt = (unsigned*)d_ws;                 // 1024 uints
    float* zbT    = (float*)((char*)d_ws + 4096);    // [GRP][MM][BR]

    hipFuncSetAttribute((const void*)fista,
                        hipFuncAttributeMaxDynamicSharedMemorySize, SMEM_BYTES);
    prefill<<<(GRP * ZG + 255) / 256, 256, 0, stream>>>(x, zbT, cnt);
    fista<<<GRID, THREADS, SMEM_BYTES, stream>>>(x, mat, lam, out, zbT, cnt);
}

// Round 6
// 13086.098 us; speedup vs baseline: 2.1925x; 1.1912x over previous
//
#include <hip/hip_runtime.h>
#include <math.h>

#define NN 5184
#define MM 81
#define BTOT 512
#define NITER 100
#define NSL 32            // n-slots: 162 rows each
#define GRP 8             // batch groups of 64 (XCD-aligned heuristic)
#define NR 162            // rows per WG
#define BR 64             // batches per group (= 64 lanes)
#define THREADS 1024
#define GRID (NSL*GRP)    // 256 WGs, 1/CU
#define RMAX 11           // waves 0,1: 11 rows; waves 2..15: 10 rows
#define YT_STRIDE 65
#define UL_STRIDE 85
#define ZB_STRIDE 84      // z row pad (336B, float4-aligned)
#define SMEM_BYTES 84000  // >80KB -> exactly 1 WG/CU (barrier co-residency)

// d_ws: cnt[1024] uints (4KB; group g at cnt[g*64], global at cnt[512]),
//       then zbuf[GRP][BR][ZB_STRIDE] (~172KB), layout [b][m], pads zero
// pbuf (u partials) = d_out [GRP][NSL][BR][MM] = 5.3MB (< 10.6MB out)

__global__ void prefill(const float* __restrict__ x, float* __restrict__ zbuf,
                        unsigned* __restrict__ cnt) {
    int i = blockIdx.x * 256 + threadIdx.x;
    if (i < GRP * BR * ZB_STRIDE) {
        int gb = i / ZB_STRIDE, m = i - gb * ZB_STRIDE;   // gb = g*BR+b
        zbuf[i] = (m < MM) ? x[(size_t)gb * MM + m] : 0.f;
    }
    if (i < 1024) cnt[i] = 0u;
}

__device__ __forceinline__ void grid_barrier(unsigned* cnt, unsigned target) {
    __syncthreads();
    if (threadIdx.x == 0) {
        __hip_atomic_fetch_add(cnt, 1u, __ATOMIC_ACQ_REL, __HIP_MEMORY_SCOPE_AGENT);
        while (__hip_atomic_load(cnt, __ATOMIC_ACQUIRE, __HIP_MEMORY_SCOPE_AGENT) < target)
            __builtin_amdgcn_s_sleep(2);
    }
    __syncthreads();
}

__global__ __launch_bounds__(THREADS, 4) void fista(
        const float* __restrict__ x, const float* __restrict__ mat,
        const float* __restrict__ lam, float* __restrict__ out,
        float* __restrict__ zbuf, unsigned* __restrict__ cntbase) {
    extern __shared__ float sm[];
    float* yT  = sm;                             // [NR][YT_STRIDE] (final only)
    float* uL  = sm + NR * YT_STRIDE;            // [BR][UL_STRIDE]
    float* red = uL + BR * UL_STRIDE;            // [672]

    const int tid  = threadIdx.x;
    const int wv   = tid >> 6, lane = tid & 63;
    const int g    = blockIdx.x & 7;
    const int slot = blockIdx.x >> 3;
    const int b0   = g * BR;
    const int n0   = slot * NR;
    const float thr = lam[0];
    unsigned* cnt  = cntbase + g * 64;           // per-group counter
    unsigned* gcnt = cntbase + 512;              // global counter
    float* zg = zbuf + (size_t)g * BR * ZB_STRIDE;       // group z [b][84]
    const float* zrow = zg + (size_t)lane * ZB_STRIDE;   // lane's z row
    float* pbuf = out;                           // [GRP][NSL][BR][MM]

    for (int i = tid; i < BR * UL_STRIDE; i += THREADS) uL[i] = 0.f;
    __syncthreads();

    // wave row partition: waves 0,1 get 11 rows, rest 10 (2*11 + 14*10 = 162)
    const int rbeg = wv * 10 + (wv < 2 ? wv : 2);
    const int rcnt = (wv < 2) ? 11 : 10;

    float ya[RMAX];                              // y state: registers, all 100 iters
#pragma unroll
    for (int r = 0; r < RMAX; ++r) ya[r] = 0.f;

    float t = 1.f;
    unsigned bar = 0;

    for (int it = 0; it < NITER; ++it) {
        float tn = (1.f + sqrtf(1.f + t * t)) * 0.5f;
        float coef = (t - 1.f) / tn;
        t = tn;
        const bool dob = (it != NITER - 1);

        // ---- Phase A: accA[r] = <mat_row, z_lane>, chunked by 16 ----
        float accA[RMAX];
#pragma unroll
        for (int r = 0; r < RMAX; ++r) accA[r] = 0.f;

#pragma unroll
        for (int c = 0; c < 5; ++c) {
            float zc[16];
            {
                const float4* zp = (const float4*)(zrow + c * 16);
                *(float4*)&zc[0]  = zp[0];
                *(float4*)&zc[4]  = zp[1];
                *(float4*)&zc[8]  = zp[2];
                *(float4*)&zc[12] = zp[3];
            }
#pragma unroll
            for (int r = 0; r < RMAX; ++r) {
                if (r < rcnt) {   // wave-uniform guard
                    const float* mrow = mat +
                        (size_t)__builtin_amdgcn_readfirstlane(n0 + rbeg + r) * MM + c * 16;
#pragma unroll
                    for (int j = 0; j < 16; ++j)
                        accA[r] = fmaf(mrow[j], zc[j], accA[r]);
                }
            }
        }
        {   // tail m = 80
            float z80 = zrow[80];
#pragma unroll
            for (int r = 0; r < RMAX; ++r) {
                if (r < rcnt) {
                    const float* mrow = mat +
                        (size_t)__builtin_amdgcn_readfirstlane(n0 + rbeg + r) * MM;
                    accA[r] = fmaf(mrow[80], z80, accA[r]);
                }
            }
        }

        // ---- y update (registers) ----
#pragma unroll
        for (int r = 0; r < RMAX; ++r) {
            if (r < rcnt) {
                float yo = ya[r];
                float w  = yo + accA[r];                               // MU = 1
                float yn = fmaxf(w - thr, 0.f) + fminf(w + thr, 0.f);  // soft-thresh
                ya[r] = yn + coef * (yn - yo);                         // momentum
            }
        }
        if (!dob) break;

        // ---- Phase B: uc[16] per chunk, rows x SGPR mat, then ds_add_f32 ----
#pragma unroll
        for (int c = 0; c < 5; ++c) {
            float uc[16];
#pragma unroll
            for (int j = 0; j < 16; ++j) uc[j] = 0.f;
#pragma unroll
            for (int r = 0; r < RMAX; ++r) {
                if (r < rcnt) {
                    const float* mrow = mat +
                        (size_t)__builtin_amdgcn_readfirstlane(n0 + rbeg + r) * MM + c * 16;
#pragma unroll
                    for (int j = 0; j < 16; ++j)
                        uc[j] = fmaf(mrow[j], ya[r], uc[j]);
                }
            }
#pragma unroll
            for (int j = 0; j < 16; ++j)
                __hip_atomic_fetch_add(&uL[lane * UL_STRIDE + c * 16 + j], uc[j],
                                       __ATOMIC_RELAXED, __HIP_MEMORY_SCOPE_WORKGROUP);
        }
        {   // tail m = 80
            float u80 = 0.f;
#pragma unroll
            for (int r = 0; r < RMAX; ++r) {
                if (r < rcnt) {
                    const float* mrow = mat +
                        (size_t)__builtin_amdgcn_readfirstlane(n0 + rbeg + r) * MM;
                    u80 = fmaf(mrow[80], ya[r], u80);
                }
            }
            __hip_atomic_fetch_add(&uL[lane * UL_STRIDE + 80], u80,
                                   __ATOMIC_RELAXED, __HIP_MEMORY_SCOPE_WORKGROUP);
        }
        __syncthreads();

        // ---- write WG's u partial to pbuf (coalesced) ----
        {
            size_t base = (((size_t)g * NSL + slot) * BR) * MM;
            for (int i = tid; i < BR * MM; i += THREADS) {
                int b = i / MM, m = i - b * MM;
                pbuf[base + i] = uL[b * UL_STRIDE + m];
            }
        }
        __syncthreads();
        for (int i = tid; i < BR * UL_STRIDE; i += THREADS) uL[i] = 0.f;

        grid_barrier(cnt, ++bar * 32u);

        // ---- Phase R: reduce 32 slices for batches 2*slot, 2*slot+1; z = x - u ----
        if (tid < 648) {
            int sq = tid & 3, e = tid >> 2;          // e 0..161
            int b2 = (e >= MM) ? 1 : 0;
            int m  = e - b2 * MM;
            int bg = 2 * slot + b2;
            const float* pp = pbuf + (((size_t)g * NSL) * BR + bg) * MM + m;
            float ssum = 0.f;
#pragma unroll
            for (int s2 = 0; s2 < 8; ++s2)
                ssum += pp[(size_t)(sq * 8 + s2) * BR * MM];
            red[tid] = ssum;
        }
        __syncthreads();
        if (tid < 162) {
            int b2 = (tid >= MM) ? 1 : 0;
            int m  = tid - b2 * MM;
            int bg = 2 * slot + b2;
            float tot = red[tid*4] + red[tid*4+1] + red[tid*4+2] + red[tid*4+3];
            zg[(size_t)bg * ZB_STRIDE + m] = x[(size_t)(b0 + bg) * MM + m] - tot;
        }

        grid_barrier(cnt, ++bar * 32u);
    }

    // ---- final y -> LDS; GLOBAL barrier (pbuf consumed); transpose-write out ----
#pragma unroll
    for (int r = 0; r < RMAX; ++r)
        if (r < rcnt) yT[(rbeg + r) * YT_STRIDE + lane] = ya[r];
    grid_barrier(gcnt, (unsigned)GRID);
    for (int i = tid; i < BR * NR; i += THREADS) {
        int b = i / NR, n = i - b * NR;
        out[(size_t)(b0 + b) * NN + n0 + n] = yT[n * YT_STRIDE + b];
    }
}

extern "C" void kernel_launch(void* const* d_in, const int* in_sizes, int n_in,
                              void* d_out, int out_size, void* d_ws, size_t ws_size,
                              hipStream_t stream) {
    const float* x   = (const float*)d_in[0];   // [512][81]
    const float* mat = (const float*)d_in[1];   // [5184][81]
    const float* lam = (const float*)d_in[2];   // [1]
    float* out = (float*)d_out;                 // [512][5184]

    unsigned* cnt = (unsigned*)d_ws;                 // 1024 uints
    float* zbuf   = (float*)((char*)d_ws + 4096);    // [GRP][BR][ZB_STRIDE]

    hipFuncSetAttribute((const void*)fista,
                        hipFuncAttributeMaxDynamicSharedMemorySize, SMEM_BYTES);
    prefill<<<(GRP * BR * ZB_STRIDE + 255) / 256, 256, 0, stream>>>(x, zbuf, cnt);
    fista<<<GRID, THREADS, SMEM_BYTES, stream>>>(x, mat, lam, out, zbuf, cnt);
}

// Round 7
// 12098.918 us; speedup vs baseline: 2.3714x; 1.0816x over previous
//
#include <hip/hip_runtime.h>
#include <math.h>

#define NN 5184
#define MM 81
#define BTOT 512
#define NITER 100
#define NSL 32            // n-slots: 162 rows each
#define GRP 8             // batch groups of 64
#define NR 162            // rows per WG
#define BR 64             // batches per group (= 64 lanes)
#define THREADS 1024
#define GRID (NSL*GRP)    // 256 WGs
#define RMAX 11           // waves 0,1: 11 rows; waves 2..15: 10 rows
#define UL_STRIDE 85
#define YT_STRIDE 65

// ============ multi-launch path (preferred) ============
// d_ws: yT[NN][BTOT] (10.6MB) + z[BTOT][MM] (166KB)
// d_out: pbuf[GRP][NSL][BR][MM] = 5.3MB during iters; final y at the end
#define WS_NEED ((size_t)(NN*(size_t)BTOT + (size_t)BTOT*MM) * 4)

__global__ void kprep(const float* __restrict__ x, float* __restrict__ z) {
    int i = blockIdx.x * 256 + threadIdx.x;     // 162*256 == BTOT*MM exactly
    z[i] = x[i];
}

template <bool FINAL>
__global__ __launch_bounds__(THREADS) void kAB(
        const float* __restrict__ mat, const float* __restrict__ lam,
        float* __restrict__ yT, const float* __restrict__ z,
        float* __restrict__ pbuf, float* __restrict__ out,
        int it, float coef) {
    __shared__ float zL[MM * BR];                       // z transposed [m][b]
    __shared__ float uL[FINAL ? 1 : BR * UL_STRIDE];    // phase-B accum
    __shared__ float yTr[FINAL ? NR * YT_STRIDE : 1];   // final transpose

    const int tid  = threadIdx.x;
    const int wv   = tid >> 6, lane = tid & 63;
    const int g    = blockIdx.x & 7;
    const int slot = blockIdx.x >> 3;
    const int n0   = slot * NR;
    const float thr = lam[0];

    // stage z (transposed): zL[m*64+b] = z[(g*64+b)*81+m]; coalesced global read
    for (int i = tid; i < MM * BR; i += THREADS) {
        int b = i / MM, m = i - b * MM;
        zL[m * BR + b] = z[(size_t)(g * BR + b) * MM + m];
    }
    if (!FINAL)
        for (int i = tid; i < BR * UL_STRIDE; i += THREADS) uL[i] = 0.f;
    __syncthreads();

    // wave row partition: waves 0,1 get 11 rows, rest 10 (2*11 + 14*10 = 162)
    const int rbeg = wv * 10 + (wv < 2 ? wv : 2);
    const int rcnt = (wv < 2) ? 11 : 10;

    // ---- Phase A: accA[r] = <mat_row, z_lane>, strip-mined by 16 ----
    float accA[RMAX];
#pragma unroll
    for (int r = 0; r < RMAX; ++r) accA[r] = 0.f;

#pragma unroll
    for (int c = 0; c < 5; ++c) {
        float zc[16];
#pragma unroll
        for (int j = 0; j < 16; ++j) zc[j] = zL[(c * 16 + j) * BR + lane];  // 2-way max
#pragma unroll
        for (int r = 0; r < RMAX; ++r) {
            if (r < rcnt) {   // wave-uniform guard
                const float* mrow = mat +
                    (size_t)__builtin_amdgcn_readfirstlane(n0 + rbeg + r) * MM + c * 16;
#pragma unroll
                for (int j = 0; j < 16; ++j)
                    accA[r] = fmaf(mrow[j], zc[j], accA[r]);
            }
        }
    }
    {   // tail m = 80
        float z80 = zL[80 * BR + lane];
#pragma unroll
        for (int r = 0; r < RMAX; ++r) {
            if (r < rcnt) {
                const float* mrow = mat +
                    (size_t)__builtin_amdgcn_readfirstlane(n0 + rbeg + r) * MM;
                accA[r] = fmaf(mrow[80], z80, accA[r]);
            }
        }
    }

    // ---- y update: read yT, soft-thresh + momentum, write back ----
    float ya[RMAX];
#pragma unroll
    for (int r = 0; r < RMAX; ++r) ya[r] = 0.f;
#pragma unroll
    for (int r = 0; r < RMAX; ++r) {
        if (r < rcnt) {
            const int row = rbeg + r;
            const size_t yi = (size_t)(n0 + row) * BTOT + g * BR + lane;  // coalesced
            float yo = (it == 0) ? 0.f : yT[yi];
            float w  = yo + accA[r];                                   // MU = 1
            float yn = fmaxf(w - thr, 0.f) + fminf(w + thr, 0.f);      // soft-thresh
            float yv = yn + coef * (yn - yo);                          // momentum
            ya[r] = yv;
            if (!FINAL) yT[yi] = yv;
        }
    }

    if (FINAL) {
        // final y -> LDS transpose -> coalesced out[b][n]
#pragma unroll
        for (int r = 0; r < RMAX; ++r)
            if (r < rcnt) yTr[(rbeg + r) * YT_STRIDE + lane] = ya[r];
        __syncthreads();
        for (int i = tid; i < BR * NR; i += THREADS) {
            int b = i / NR, n = i - b * NR;
            out[(size_t)(g * BR + b) * NN + n0 + n] = yTr[n * YT_STRIDE + b];
        }
        return;
    }

    // ---- Phase B: uc[16] per chunk over owned rows; ds_add reduce ----
#pragma unroll
    for (int c = 0; c < 5; ++c) {
        float uc[16];
#pragma unroll
        for (int j = 0; j < 16; ++j) uc[j] = 0.f;
#pragma unroll
        for (int r = 0; r < RMAX; ++r) {
            if (r < rcnt) {
                const float* mrow = mat +
                    (size_t)__builtin_amdgcn_readfirstlane(n0 + rbeg + r) * MM + c * 16;
#pragma unroll
                for (int j = 0; j < 16; ++j)
                    uc[j] = fmaf(mrow[j], ya[r], uc[j]);
            }
        }
#pragma unroll
        for (int j = 0; j < 16; ++j)
            __hip_atomic_fetch_add(&uL[lane * UL_STRIDE + c * 16 + j], uc[j],
                                   __ATOMIC_RELAXED, __HIP_MEMORY_SCOPE_WORKGROUP);
    }
    {   // tail m = 80
        float u80 = 0.f;
#pragma unroll
        for (int r = 0; r < RMAX; ++r) {
            if (r < rcnt) {
                const float* mrow = mat +
                    (size_t)__builtin_amdgcn_readfirstlane(n0 + rbeg + r) * MM;
                u80 = fmaf(mrow[80], ya[r], u80);
            }
        }
        __hip_atomic_fetch_add(&uL[lane * UL_STRIDE + 80], u80,
                               __ATOMIC_RELAXED, __HIP_MEMORY_SCOPE_WORKGROUP);
    }
    __syncthreads();

    // ---- write WG's u partial to pbuf (coalesced) ----
    {
        size_t base = (((size_t)g * NSL + slot) * BR) * MM;
        for (int i = tid; i < BR * MM; i += THREADS) {
            int b = i / MM, m = i - b * MM;
            pbuf[base + i] = uL[b * UL_STRIDE + m];
        }
    }
}

__global__ void kR(const float* __restrict__ x, const float* __restrict__ pbuf,
                   float* __restrict__ z) {
    int i = blockIdx.x * 256 + threadIdx.x;     // 162*256 == BTOT*MM exactly
    int bg = i / MM, m = i - bg * MM;
    int g = bg >> 6, bl = bg & 63;
    const float* pp = pbuf + ((size_t)(g * NSL) * BR + bl) * MM + m;
    float s = 0.f;
#pragma unroll
    for (int slot = 0; slot < NSL; ++slot)
        s += pp[(size_t)slot * BR * MM];
    z[i] = x[i] - s;
}

// ============ fallback: r6 persistent kernel (ws too small) ============
#define ZB_STRIDE 84
#define SMEM_BYTES 84000

__global__ void prefill_fb(const float* __restrict__ x, float* __restrict__ zbuf,
                           unsigned* __restrict__ cnt) {
    int i = blockIdx.x * 256 + threadIdx.x;
    if (i < GRP * BR * ZB_STRIDE) {
        int gb = i / ZB_STRIDE, m = i - gb * ZB_STRIDE;
        zbuf[i] = (m < MM) ? x[(size_t)gb * MM + m] : 0.f;
    }
    if (i < 1024) cnt[i] = 0u;
}

__device__ __forceinline__ void grid_barrier(unsigned* cnt, unsigned target) {
    __syncthreads();
    if (threadIdx.x == 0) {
        __hip_atomic_fetch_add(cnt, 1u, __ATOMIC_ACQ_REL, __HIP_MEMORY_SCOPE_AGENT);
        while (__hip_atomic_load(cnt, __ATOMIC_ACQUIRE, __HIP_MEMORY_SCOPE_AGENT) < target)
            __builtin_amdgcn_s_sleep(2);
    }
    __syncthreads();
}

__global__ __launch_bounds__(THREADS, 4) void fista_fb(
        const float* __restrict__ x, const float* __restrict__ mat,
        const float* __restrict__ lam, float* __restrict__ out,
        float* __restrict__ zbuf, unsigned* __restrict__ cntbase) {
    extern __shared__ float sm[];
    float* yT  = sm;
    float* uL  = sm + NR * YT_STRIDE;
    float* red = uL + BR * UL_STRIDE;

    const int tid  = threadIdx.x;
    const int wv   = tid >> 6, lane = tid & 63;
    const int g    = blockIdx.x & 7;
    const int slot = blockIdx.x >> 3;
    const int b0   = g * BR;
    const int n0   = slot * NR;
    const float thr = lam[0];
    unsigned* cnt  = cntbase + g * 64;
    unsigned* gcnt = cntbase + 512;
    float* zg = zbuf + (size_t)g * BR * ZB_STRIDE;
    const float* zrow = zg + (size_t)lane * ZB_STRIDE;
    float* pbuf = out;

    for (int i = tid; i < BR * UL_STRIDE; i += THREADS) uL[i] = 0.f;
    __syncthreads();

    const int rbeg = wv * 10 + (wv < 2 ? wv : 2);
    const int rcnt = (wv < 2) ? 11 : 10;

    float ya[RMAX];
#pragma unroll
    for (int r = 0; r < RMAX; ++r) ya[r] = 0.f;

    float t = 1.f;
    unsigned bar = 0;

    for (int it = 0; it < NITER; ++it) {
        float tn = (1.f + sqrtf(1.f + t * t)) * 0.5f;
        float coef = (t - 1.f) / tn;
        t = tn;
        const bool dob = (it != NITER - 1);

        float accA[RMAX];
#pragma unroll
        for (int r = 0; r < RMAX; ++r) accA[r] = 0.f;
#pragma unroll
        for (int c = 0; c < 5; ++c) {
            float zc[16];
            const float4* zp = (const float4*)(zrow + c * 16);
            *(float4*)&zc[0]  = zp[0];
            *(float4*)&zc[4]  = zp[1];
            *(float4*)&zc[8]  = zp[2];
            *(float4*)&zc[12] = zp[3];
#pragma unroll
            for (int r = 0; r < RMAX; ++r) {
                if (r < rcnt) {
                    const float* mrow = mat +
                        (size_t)__builtin_amdgcn_readfirstlane(n0 + rbeg + r) * MM + c * 16;
#pragma unroll
                    for (int j = 0; j < 16; ++j)
                        accA[r] = fmaf(mrow[j], zc[j], accA[r]);
                }
            }
        }
        {
            float z80 = zrow[80];
#pragma unroll
            for (int r = 0; r < RMAX; ++r) {
                if (r < rcnt) {
                    const float* mrow = mat +
                        (size_t)__builtin_amdgcn_readfirstlane(n0 + rbeg + r) * MM;
                    accA[r] = fmaf(mrow[80], z80, accA[r]);
                }
            }
        }
#pragma unroll
        for (int r = 0; r < RMAX; ++r) {
            if (r < rcnt) {
                float yo = ya[r];
                float w  = yo + accA[r];
                float yn = fmaxf(w - thr, 0.f) + fminf(w + thr, 0.f);
                ya[r] = yn + coef * (yn - yo);
            }
        }
        if (!dob) break;

#pragma unroll
        for (int c = 0; c < 5; ++c) {
            float uc[16];
#pragma unroll
            for (int j = 0; j < 16; ++j) uc[j] = 0.f;
#pragma unroll
            for (int r = 0; r < RMAX; ++r) {
                if (r < rcnt) {
                    const float* mrow = mat +
                        (size_t)__builtin_amdgcn_readfirstlane(n0 + rbeg + r) * MM + c * 16;
#pragma unroll
                    for (int j = 0; j < 16; ++j)
                        uc[j] = fmaf(mrow[j], ya[r], uc[j]);
                }
            }
#pragma unroll
            for (int j = 0; j < 16; ++j)
                __hip_atomic_fetch_add(&uL[lane * UL_STRIDE + c * 16 + j], uc[j],
                                       __ATOMIC_RELAXED, __HIP_MEMORY_SCOPE_WORKGROUP);
        }
        {
            float u80 = 0.f;
#pragma unroll
            for (int r = 0; r < RMAX; ++r) {
                if (r < rcnt) {
                    const float* mrow = mat +
                        (size_t)__builtin_amdgcn_readfirstlane(n0 + rbeg + r) * MM;
                    u80 = fmaf(mrow[80], ya[r], u80);
                }
            }
            __hip_atomic_fetch_add(&uL[lane * UL_STRIDE + 80], u80,
                                   __ATOMIC_RELAXED, __HIP_MEMORY_SCOPE_WORKGROUP);
        }
        __syncthreads();
        {
            size_t base = (((size_t)g * NSL + slot) * BR) * MM;
            for (int i = tid; i < BR * MM; i += THREADS) {
                int b = i / MM, m = i - b * MM;
                pbuf[base + i] = uL[b * UL_STRIDE + m];
            }
        }
        __syncthreads();
        for (int i = tid; i < BR * UL_STRIDE; i += THREADS) uL[i] = 0.f;

        grid_barrier(cnt, ++bar * 32u);

        if (tid < 648) {
            int sq = tid & 3, e = tid >> 2;
            int b2 = (e >= MM) ? 1 : 0;
            int m  = e - b2 * MM;
            int bg = 2 * slot + b2;
            const float* pp = pbuf + (((size_t)g * NSL) * BR + bg) * MM + m;
            float ssum = 0.f;
#pragma unroll
            for (int s2 = 0; s2 < 8; ++s2)
                ssum += pp[(size_t)(sq * 8 + s2) * BR * MM];
            red[tid] = ssum;
        }
        __syncthreads();
        if (tid < 162) {
            int b2 = (tid >= MM) ? 1 : 0;
            int m  = tid - b2 * MM;
            int bg = 2 * slot + b2;
            float tot = red[tid*4] + red[tid*4+1] + red[tid*4+2] + red[tid*4+3];
            zg[(size_t)bg * ZB_STRIDE + m] = x[(size_t)(b0 + bg) * MM + m] - tot;
        }
        grid_barrier(cnt, ++bar * 32u);
    }

#pragma unroll
    for (int r = 0; r < RMAX; ++r)
        if (r < rcnt) yT[(rbeg + r) * YT_STRIDE + lane] = ya[r];
    grid_barrier(gcnt, (unsigned)GRID);
    for (int i = tid; i < BR * NR; i += THREADS) {
        int b = i / NR, n = i - b * NR;
        out[(size_t)(b0 + b) * NN + n0 + n] = yT[n * YT_STRIDE + b];
    }
}

// ============ launch ============
extern "C" void kernel_launch(void* const* d_in, const int* in_sizes, int n_in,
                              void* d_out, int out_size, void* d_ws, size_t ws_size,
                              hipStream_t stream) {
    const float* x   = (const float*)d_in[0];   // [512][81]
    const float* mat = (const float*)d_in[1];   // [5184][81]
    const float* lam = (const float*)d_in[2];   // [1]
    float* out = (float*)d_out;                 // [512][5184]

    if (ws_size >= WS_NEED) {
        float* yT = (float*)d_ws;                       // [NN][BTOT]
        float* z  = yT + (size_t)NN * BTOT;             // [BTOT][MM]
        float* pbuf = out;                              // [GRP][NSL][BR][MM]

        kprep<<<162, 256, 0, stream>>>(x, z);
        float t = 1.f;
        for (int it = 0; it < NITER; ++it) {
            float tn = (1.f + sqrtf(1.f + t * t)) * 0.5f;
            float coef = (t - 1.f) / tn;
            t = tn;
            if (it < NITER - 1) {
                kAB<false><<<GRID, THREADS, 0, stream>>>(mat, lam, yT, z, pbuf, out, it, coef);
                kR<<<162, 256, 0, stream>>>(x, pbuf, z);
            } else {
                kAB<true><<<GRID, THREADS, 0, stream>>>(mat, lam, yT, z, pbuf, out, it, coef);
            }
        }
    } else {
        unsigned* cnt = (unsigned*)d_ws;
        float* zbuf   = (float*)((char*)d_ws + 4096);
        hipFuncSetAttribute((const void*)fista_fb,
                            hipFuncAttributeMaxDynamicSharedMemorySize, SMEM_BYTES);
        prefill_fb<<<(GRP * BR * ZB_STRIDE + 255) / 256, 256, 0, stream>>>(x, zbuf, cnt);
        fista_fb<<<GRID, THREADS, SMEM_BYTES, stream>>>(x, mat, lam, out, zbuf, cnt);
    }
}

// Round 8
// 11775.579 us; speedup vs baseline: 2.4365x; 1.0275x over previous
//
#include <hip/hip_runtime.h>
#include <math.h>

#define NN 5184
#define MM 81
#define BTOT 512
#define NITER 100
#define NSL 32            // n-slots: 162 rows each
#define GRP 8             // batch groups of 64 (bid&7 -> same XCD heuristic)
#define NR 162            // rows per WG
#define BR 64             // batches per group (= 64 lanes)
#define THREADS 1024
#define GRID (NSL*GRP)    // 256 WGs, 1/CU via 84KB LDS
#define RMAX 11           // waves 0,1: 11 rows; waves 2..15: 10 rows
#define UL_STRIDE 85
#define YT_STRIDE 65
#define ZG (MM*BR)        // 5184 floats per group, layout [m][b]
#define SMEM_BYTES 84000  // force 1 WG/CU (co-residency for spin flags)

// d_ws: cnt[1024] uints (4KB): flag0[g]=cnt[g*32], flag1[g]=cnt[256+g*32],
//       gflag=cnt[512]; then zT[GRP][MM][BR] (166KB)
// pbuf = d_out [GRP][NSL][BR][MM] = 5.3MB during iters; final y written last.

// ---- L2-bypass (LLC coherence point) accessors: relaxed system scope ----
__device__ __forceinline__ float sysload(const float* p) {
    return __hip_atomic_load(p, __ATOMIC_RELAXED, __HIP_MEMORY_SCOPE_SYSTEM);
}
__device__ __forceinline__ void sysstore(float* p, float v) {
    __hip_atomic_store(p, v, __ATOMIC_RELAXED, __HIP_MEMORY_SCOPE_SYSTEM);
}
__device__ __forceinline__ void drain_vmem() {
    asm volatile("s_waitcnt vmcnt(0)" ::: "memory");
}

__global__ void prefill(const float* __restrict__ x, float* __restrict__ zT,
                        unsigned* __restrict__ cnt) {
    int i = blockIdx.x * 256 + threadIdx.x;
    if (i < GRP * ZG) {
        int g = i / ZG, r = i - g * ZG;
        int m = r >> 6, b = r & 63;
        zT[i] = x[(size_t)(g * BR + b) * MM + m];   // normal store; kernel-end flush
    }
    if (i < 1024) cnt[i] = 0u;
}

// publish: (payload already stored+drained by caller) tid0 bumps flag, then all
// WGs poll to target. Relaxed bypass poll; rare acquire fallback for liveness.
__device__ __forceinline__ void flag_sync(unsigned* flag, unsigned target, int tid) {
    __syncthreads();
    if (tid == 0) {
        __hip_atomic_fetch_add(flag, 1u, __ATOMIC_RELAXED, __HIP_MEMORY_SCOPE_SYSTEM);
        int spins = 0;
        while (__hip_atomic_load(flag, __ATOMIC_RELAXED, __HIP_MEMORY_SCOPE_SYSTEM) < target) {
            if ((++spins & 255) == 0)
                (void)__hip_atomic_load(flag, __ATOMIC_ACQUIRE, __HIP_MEMORY_SCOPE_SYSTEM);
            __builtin_amdgcn_s_sleep(1);
        }
    }
    __syncthreads();
}

__global__ __launch_bounds__(THREADS, 4) void fista(
        const float* __restrict__ x, const float* __restrict__ mat,
        const float* __restrict__ lam, float* __restrict__ out,
        float* __restrict__ zT, unsigned* __restrict__ cntbase) {
    extern __shared__ float sm[];
    float* zL = sm;                // [MM][BR] = 5184 floats (also red[], also yTr)
    float* uL = sm + ZG;           // [BR][UL_STRIDE] = 5440 floats

    const int tid  = threadIdx.x;
    const int wv   = tid >> 6, lane = tid & 63;
    const int g    = blockIdx.x & 7;
    const int slot = blockIdx.x >> 3;
    const int n0   = slot * NR;
    const float thr = lam[0];
    unsigned* flag0 = cntbase + g * 32;
    unsigned* flag1 = cntbase + 256 + g * 32;
    unsigned* gflag = cntbase + 512;
    float* zg   = zT + (size_t)g * ZG;           // group z, [m][b]
    float* pbuf = out;                           // [GRP][NSL][BR][MM]

    for (int i = tid; i < BR * UL_STRIDE; i += THREADS) uL[i] = 0.f;

    // wave row partition: waves 0,1 get 11 rows, rest 10 (2*11 + 14*10 = 162)
    const int rbeg = wv * 10 + (wv < 2 ? wv : 2);
    const int rcnt = (wv < 2) ? 11 : 10;

    float ya[RMAX];                              // y state in registers, all iters
#pragma unroll
    for (int r = 0; r < RMAX; ++r) ya[r] = 0.f;

    float t = 1.f;

    for (int it = 0; it < NITER; ++it) {
        float tn = (1.f + sqrtf(1.f + t * t)) * 0.5f;
        float coef = (t - 1.f) / tn;
        t = tn;
        const bool dob = (it != NITER - 1);

        // ---- stage z: bypass-load zT (coalesced, [m][b] order) into LDS ----
        __syncthreads();                         // zL reuse safe (red/prev dead)
        for (int i = tid; i < ZG; i += THREADS) zL[i] = sysload(zg + i);
        if (!dob) {
            // last iter: certify my group's pbuf reads (it=98 Phase R) done
            if (tid == 0)
                __hip_atomic_fetch_add(gflag, 1u, __ATOMIC_RELAXED,
                                       __HIP_MEMORY_SCOPE_SYSTEM);
        }
        __syncthreads();

        // ---- Phase A: accA[r] = <mat_row, z_lane>, strip-mined by 16 ----
        float accA[RMAX];
#pragma unroll
        for (int r = 0; r < RMAX; ++r) accA[r] = 0.f;

#pragma unroll
        for (int c = 0; c < 5; ++c) {
            float zc[16];
#pragma unroll
            for (int j = 0; j < 16; ++j) zc[j] = zL[(c * 16 + j) * BR + lane];
#pragma unroll
            for (int r = 0; r < RMAX; ++r) {
                if (r < rcnt) {   // wave-uniform guard -> s_load mat row chunk
                    const float* mrow = mat +
                        (size_t)__builtin_amdgcn_readfirstlane(n0 + rbeg + r) * MM + c * 16;
#pragma unroll
                    for (int j = 0; j < 16; ++j)
                        accA[r] = fmaf(mrow[j], zc[j], accA[r]);
                }
            }
        }
        {   // tail m = 80
            float z80 = zL[80 * BR + lane];
#pragma unroll
            for (int r = 0; r < RMAX; ++r) {
                if (r < rcnt) {
                    const float* mrow = mat +
                        (size_t)__builtin_amdgcn_readfirstlane(n0 + rbeg + r) * MM;
                    accA[r] = fmaf(mrow[80], z80, accA[r]);
                }
            }
        }

        // ---- y update (registers) ----
#pragma unroll
        for (int r = 0; r < RMAX; ++r) {
            if (r < rcnt) {
                float yo = ya[r];
                float w  = yo + accA[r];                               // MU = 1
                float yn = fmaxf(w - thr, 0.f) + fminf(w + thr, 0.f);  // soft-thresh
                ya[r] = yn + coef * (yn - yo);                         // momentum
            }
        }
        if (!dob) break;

        // ---- Phase B: uc[16] per chunk over owned rows; ds_add reduce ----
#pragma unroll
        for (int c = 0; c < 5; ++c) {
            float uc[16];
#pragma unroll
            for (int j = 0; j < 16; ++j) uc[j] = 0.f;
#pragma unroll
            for (int r = 0; r < RMAX; ++r) {
                if (r < rcnt) {
                    const float* mrow = mat +
                        (size_t)__builtin_amdgcn_readfirstlane(n0 + rbeg + r) * MM + c * 16;
#pragma unroll
                    for (int j = 0; j < 16; ++j)
                        uc[j] = fmaf(mrow[j], ya[r], uc[j]);
                }
            }
#pragma unroll
            for (int j = 0; j < 16; ++j)
                __hip_atomic_fetch_add(&uL[lane * UL_STRIDE + c * 16 + j], uc[j],
                                       __ATOMIC_RELAXED, __HIP_MEMORY_SCOPE_WORKGROUP);
        }
        {   // tail m = 80
            float u80 = 0.f;
#pragma unroll
            for (int r = 0; r < RMAX; ++r) {
                if (r < rcnt) {
                    const float* mrow = mat +
                        (size_t)__builtin_amdgcn_readfirstlane(n0 + rbeg + r) * MM;
                    u80 = fmaf(mrow[80], ya[r], u80);
                }
            }
            __hip_atomic_fetch_add(&uL[lane * UL_STRIDE + 80], u80,
                                   __ATOMIC_RELAXED, __HIP_MEMORY_SCOPE_WORKGROUP);
        }
        __syncthreads();

        // ---- publish u partial: bypass-store to pbuf (coalesced) ----
        {
            size_t base = (((size_t)g * NSL + slot) * BR) * MM;
            for (int i = tid; i < BR * MM; i += THREADS) {
                int b = i / MM, m = i - b * MM;
                sysstore(&pbuf[base + i], uL[b * UL_STRIDE + m]);
            }
        }
        __syncthreads();                         // all uL ds_reads done
        for (int i = tid; i < BR * UL_STRIDE; i += THREADS) uL[i] = 0.f;
        drain_vmem();                            // payload stores at LLC
        flag_sync(flag0, 32u * (it + 1), tid);

        // ---- Phase R: reduce 32 slices for batches 2*slot, 2*slot+1 ----
        {
            float* red = zL;                     // zL dead until next stage
            if (tid < 648) {
                int sq = tid & 3, e = tid >> 2;  // e 0..161
                int b2 = (e >= MM) ? 1 : 0;
                int m  = e - b2 * MM;
                int bg = 2 * slot + b2;
                const float* pp = pbuf + (((size_t)g * NSL) * BR + bg) * MM + m;
                float ssum = 0.f;
#pragma unroll
                for (int s2 = 0; s2 < 8; ++s2)
                    ssum += sysload(pp + (size_t)(sq * 8 + s2) * BR * MM);
                red[tid] = ssum;
            }
            __syncthreads();
            if (tid < 162) {
                int b2 = (tid >= MM) ? 1 : 0;
                int m  = tid - b2 * MM;
                int bg = 2 * slot + b2;
                float tot = red[tid*4] + red[tid*4+1] + red[tid*4+2] + red[tid*4+3];
                float zv = x[(size_t)(g * BR + bg) * MM + m] - tot;   // normal x read
                sysstore(&zg[m * BR + bg], zv);                       // transposed
            }
        }
        drain_vmem();
        flag_sync(flag1, 32u * (it + 1), tid);
    }

    // ---- wait all 256 WGs done reading pbuf, then overwrite out with y ----
    if (tid == 0) {
        int spins = 0;
        while (__hip_atomic_load(gflag, __ATOMIC_RELAXED, __HIP_MEMORY_SCOPE_SYSTEM)
               < (unsigned)GRID) {
            if ((++spins & 255) == 0)
                (void)__hip_atomic_load(gflag, __ATOMIC_ACQUIRE, __HIP_MEMORY_SCOPE_SYSTEM);
            __builtin_amdgcn_s_sleep(1);
        }
    }
    __syncthreads();

    // final y -> LDS transpose (reuse sm) -> coalesced normal out write
    float* yTr = sm;                             // [NR][YT_STRIDE] = 42.1KB
#pragma unroll
    for (int r = 0; r < RMAX; ++r)
        if (r < rcnt) yTr[(rbeg + r) * YT_STRIDE + lane] = ya[r];
    __syncthreads();
    for (int i = tid; i < BR * NR; i += THREADS) {
        int b = i / NR, n = i - b * NR;
        out[(size_t)(g * BR + b) * NN + n0 + n] = yTr[n * YT_STRIDE + b];
    }
}

extern "C" void kernel_launch(void* const* d_in, const int* in_sizes, int n_in,
                              void* d_out, int out_size, void* d_ws, size_t ws_size,
                              hipStream_t stream) {
    const float* x   = (const float*)d_in[0];   // [512][81]
    const float* mat = (const float*)d_in[1];   // [5184][81]
    const float* lam = (const float*)d_in[2];   // [1]
    float* out = (float*)d_out;                 // [512][5184]

    unsigned* cnt = (unsigned*)d_ws;                 // 1024 uints
    float* zT     = (float*)((char*)d_ws + 4096);    // [GRP][MM][BR]

    hipFuncSetAttribute((const void*)fista,
                        hipFuncAttributeMaxDynamicSharedMemorySize, SMEM_BYTES);
    prefill<<<(GRP * ZG + 255) / 256, 256, 0, stream>>>(x, zT, cnt);
    fista<<<GRID, THREADS, SMEM_BYTES, stream>>>(x, mat, lam, out, zT, cnt);
}